// Round 3
// baseline (596.919 us; speedup 1.0000x reference)
//
#include <hip/hip_runtime.h>
#include <hip/hip_cooperative_groups.h>
#include <cfloat>
#include <math.h>

namespace cg = cooperative_groups;

#define IMG_B 16
#define IMG_H 1024
#define IMG_W 1280
#define NPIX (IMG_H * IMG_W)
#define BINS 256
#define NBLK 1024                 // 16 images * 64 slice-blocks
#define NTHR 256
#define FIXP 65536.0f

// ---------- helpers ----------
__device__ __forceinline__ unsigned encf(float f) {
    unsigned u = __float_as_uint(f);
    return (u >> 31) ? ~u : (u | 0x80000000u);
}
__device__ __forceinline__ float decf(unsigned u) {
    unsigned b = (u & 0x80000000u) ? (u & 0x7fffffffu) : ~u;
    return __uint_as_float(b);
}

// ws layout (bytes):
//   mom   : double[1024*4]   @ 0       (S, S2, LS, LS2 per slice-block)   32 KB
//   mmp   : uint2[1024]      @ 32768   (encoded min, max per slice-block)  8 KB
//   bhist : uint[1024*256]   @ 40960   (per-slice-block fixed-point hist)  1 MB

__global__ __launch_bounds__(NTHR, 4) void k_fused(
    const float* __restrict__ img,
    const float* __restrict__ W1, const float* __restrict__ b1,
    const float* __restrict__ W2, const float* __restrict__ b2,
    const float* __restrict__ W3, const float* __restrict__ b3,
    float* __restrict__ out,
    double* __restrict__ mom, uint2* __restrict__ mmp,
    unsigned* __restrict__ bhist)
{
    cg::grid_group grid = cg::this_grid();
    const int blk  = blockIdx.x;
    const int tid  = threadIdx.x;
    const int b    = blk >> 6;          // image
    const int sl   = blk & 63;          // 16-row slice
    const int lane = tid & 63;
    const int wv   = tid >> 6;          // 4 waves

    __shared__ float    swred[6][4];
    __shared__ unsigned lh[BINS];
    __shared__ float    sh_mm[2];
    __shared__ double   dred[4];
    __shared__ float    fred[4];
    __shared__ double   smom[4];
    __shared__ unsigned smm2[2];
    __shared__ unsigned sgm[4];
    __shared__ float    f5[5], h1[64], h2[64], lg[3];

    const float* base = img + (size_t)b * NPIX;

    // ===================== Phase 1: moments + min/max (rolling window) =====
    {
        float fs = 0.f, fs2 = 0.f, fls = 0.f, fls2 = 0.f;
        float fmn = FLT_MAX, fmx = -FLT_MAX;

        const int r0 = sl * 16 + wv * 4;                 // 4 rows per wave
        const float4* rp = (const float4*)(base + (size_t)r0 * IMG_W);
        float4 up[5], m[5], dn[5];
        #pragma unroll
        for (int k = 0; k < 5; ++k) {
            int c = k * 64 + lane;                       // float4 col 0..319
            up[k] = (r0 > 0) ? rp[c - 320] : make_float4(0.f, 0.f, 0.f, 0.f);
            m[k]  = rp[c];
        }
        #pragma unroll
        for (int i = 0; i < 4; ++i) {
            int r = r0 + i;
            const float4* nr = (const float4*)(base + (size_t)(r + 1) * IMG_W);
            #pragma unroll
            for (int k = 0; k < 5; ++k)
                dn[k] = (r < IMG_H - 1) ? nr[k * 64 + lane]
                                        : make_float4(0.f, 0.f, 0.f, 0.f);
            #pragma unroll
            for (int k = 0; k < 5; ++k) {
                float4 mm = m[k], u = up[k], d = dn[k];
                // horizontal neighbors, all in-register via shuffles
                float lin  = __shfl_up(mm.w, 1u, 64);
                float lwr  = m[k ? k - 1 : 0].w;
                lwr = __shfl(lwr, 63, 64);
                float lft  = (lane == 0) ? ((k > 0) ? lwr : 0.f) : lin;
                float rin  = __shfl_down(mm.x, 1u, 64);
                float rwr  = m[k < 4 ? k + 1 : 4].x;
                rwr = __shfl(rwr, 0, 64);
                float rgt  = (lane == 63) ? ((k < 4) ? rwr : 0.f) : rin;

                float l0 = u.x + d.x + lft  + mm.y - 4.f * mm.x;
                float l1 = u.y + d.y + mm.x + mm.z - 4.f * mm.y;
                float l2 = u.z + d.z + mm.y + mm.w - 4.f * mm.z;
                float l3 = u.w + d.w + mm.z + rgt  - 4.f * mm.w;

                fs   += (mm.x + mm.y) + (mm.z + mm.w);
                fs2  += mm.x * mm.x + mm.y * mm.y + mm.z * mm.z + mm.w * mm.w;
                fls  += (l0 + l1) + (l2 + l3);
                fls2 += l0 * l0 + l1 * l1 + l2 * l2 + l3 * l3;
                fmn = fminf(fmn, fminf(fminf(mm.x, mm.y), fminf(mm.z, mm.w)));
                fmx = fmaxf(fmx, fmaxf(fmaxf(mm.x, mm.y), fmaxf(mm.z, mm.w)));
            }
            #pragma unroll
            for (int k = 0; k < 5; ++k) { up[k] = m[k]; m[k] = dn[k]; }
        }

        for (int o = 32; o; o >>= 1) {
            fs   += __shfl_down(fs,   (unsigned)o, 64);
            fs2  += __shfl_down(fs2,  (unsigned)o, 64);
            fls  += __shfl_down(fls,  (unsigned)o, 64);
            fls2 += __shfl_down(fls2, (unsigned)o, 64);
            fmn = fminf(fmn, __shfl_down(fmn, (unsigned)o, 64));
            fmx = fmaxf(fmx, __shfl_down(fmx, (unsigned)o, 64));
        }
        if (lane == 0) {
            swred[0][wv] = fs;  swred[1][wv] = fs2;
            swred[2][wv] = fls; swred[3][wv] = fls2;
            swred[4][wv] = fmn; swred[5][wv] = fmx;
        }
        __syncthreads();
        if (tid == 0) {
            double S = 0, S2 = 0, LS = 0, LS2 = 0;
            float mn = FLT_MAX, mx = -FLT_MAX;
            for (int i = 0; i < 4; ++i) {
                S  += (double)swred[0][i]; S2  += (double)swred[1][i];
                LS += (double)swred[2][i]; LS2 += (double)swred[3][i];
                mn = fminf(mn, swred[4][i]); mx = fmaxf(mx, swred[5][i]);
            }
            mom[blk * 4 + 0] = S;  mom[blk * 4 + 1] = S2;
            mom[blk * 4 + 2] = LS; mom[blk * 4 + 3] = LS2;
            mmp[blk] = make_uint2(encf(mn), encf(mx));
        }
    }
    __threadfence();
    grid.sync();

    // ===================== Phase 2: fixed-point soft histogram =============
    {
        if (tid < 64) {
            uint2 e = mmp[b * 64 + tid];
            unsigned emn = e.x, emx = e.y;
            for (int o = 32; o; o >>= 1) {
                emn = min(emn, (unsigned)__shfl_down(emn, (unsigned)o, 64));
                emx = max(emx, (unsigned)__shfl_down(emx, (unsigned)o, 64));
            }
            if (tid == 0) { sh_mm[0] = decf(emn); sh_mm[1] = decf(emx); }
        }
        lh[tid] = 0u;
        __syncthreads();

        float fmn = sh_mm[0], fmx = sh_mm[1];
        float rng = fmx - fmn;
        if (rng == 0.f) rng = 1.f;
        float inv = 1.f / rng;

        const float4* p = (const float4*)base + (size_t)sl * 5120;  // slice
        #pragma unroll 4
        for (int i = tid; i < 5120; i += NTHR) {
            float4 v = p[i];
            #pragma unroll
            for (int j = 0; j < 4; ++j) {
                float vv = (j == 0) ? v.x : (j == 1) ? v.y : (j == 2) ? v.z : v.w;
                float x  = fminf(fmaxf((vv - fmn) * inv, 0.f), 1.f);
                float pp = x * 256.f - 0.5f;
                float fi = floorf(pp);
                int   i0 = (int)fi;
                float w1 = pp - fi;
                unsigned w1q = (unsigned)(w1 * FIXP + 0.5f);
                unsigned w0q = 65536u - w1q;
                if (i0 >= 0)        atomicAdd(&lh[i0], w0q);
                if (i0 < BINS - 1)  atomicAdd(&lh[i0 + 1], w1q);
            }
        }
        __syncthreads();
        bhist[blk * BINS + tid] = lh[tid];
    }
    __threadfence();
    grid.sync();

    // ===================== Phase 3: feats + MLP (blocks 0..15) =============
    if (blk >= IMG_B) return;
    const int ib = blk;

    double h = 0.0;
    for (int s = 0; s < 64; ++s)
        h += (double)bhist[(ib * 64 + s) * BINS + tid];

    double tot = h;
    for (int o = 32; o; o >>= 1) tot += __shfl_down(tot, (unsigned)o, 64);
    if (lane == 0) dred[wv] = tot;
    __syncthreads();
    tot = dred[0] + dred[1] + dred[2] + dred[3];

    double hv = h * (1.0 / 65536.0);
    double tv = tot * (1.0 / 65536.0);
    float hn = (float)(hv / (tv + 1e-10));
    float ce = hn * log2f(hn + 1e-10f);
    for (int o = 32; o; o >>= 1) ce += __shfl_down(ce, (unsigned)o, 64);
    if (lane == 0) fred[wv] = ce;

    if (tid < 64) {
        double q0 = mom[(ib * 64 + tid) * 4 + 0];
        double q1 = mom[(ib * 64 + tid) * 4 + 1];
        double q2 = mom[(ib * 64 + tid) * 4 + 2];
        double q3 = mom[(ib * 64 + tid) * 4 + 3];
        uint2 e = mmp[ib * 64 + tid];
        unsigned emn = e.x, emx = e.y;
        for (int o = 32; o; o >>= 1) {
            q0 += __shfl_down(q0, (unsigned)o, 64);
            q1 += __shfl_down(q1, (unsigned)o, 64);
            q2 += __shfl_down(q2, (unsigned)o, 64);
            q3 += __shfl_down(q3, (unsigned)o, 64);
            emn = min(emn, (unsigned)__shfl_down(emn, (unsigned)o, 64));
            emx = max(emx, (unsigned)__shfl_down(emx, (unsigned)o, 64));
        }
        if (tid == 0) {
            smom[0] = q0; smom[1] = q1; smom[2] = q2; smom[3] = q3;
            smm2[0] = emn; smm2[1] = emx;
        }
    }
    {   // global max over all 1024 slice maxes (scale decision)
        unsigned g = max(max(mmp[tid].y, mmp[256 + tid].y),
                         max(mmp[512 + tid].y, mmp[768 + tid].y));
        for (int o = 32; o; o >>= 1)
            g = max(g, (unsigned)__shfl_down(g, (unsigned)o, 64));
        if (lane == 0) sgm[wv] = g;
    }
    __syncthreads();

    if (tid == 0) {
        float ent = -(fred[0] + fred[1] + fred[2] + fred[3]) / 8.f;
        float gmax = decf(max(max(sgm[0], sgm[1]), max(sgm[2], sgm[3])));
        float sc = (gmax > 1.f) ? (1.f / 16383.f) : 1.f;
        double N = (double)NPIX;
        double S = smom[0], S2 = smom[1], LS = smom[2], LS2 = smom[3];
        double sc2 = (double)sc * (double)sc;
        float var  = (float)((S2  - S  * S  / N) / (N - 1.0) * sc2);
        float lvar = (float)((LS2 - LS * LS / N) / (N - 1.0) * sc2);
        float mn = decf(smm2[0]) * sc;
        float mx = decf(smm2[1]) * sc;
        float* fo = out + 64 + ib * 5;
        fo[0] = var; fo[1] = mn; fo[2] = mx; fo[3] = ent; fo[4] = lvar;
        f5[0] = var; f5[1] = mn; f5[2] = mx; f5[3] = ent; f5[4] = lvar;
    }
    __syncthreads();

    // --- tiny MLP on wave 0 ---
    if (tid < 64) {
        float a = b1[tid];
        #pragma unroll
        for (int k = 0; k < 5; ++k) a += W1[tid * 5 + k] * f5[k];
        h1[tid] = fmaxf(a, 0.f);
    }
    __syncthreads();
    if (tid < 64) {
        float a2 = b2[tid];
        #pragma unroll
        for (int k = 0; k < 64; ++k) a2 += W2[tid * 64 + k] * h1[k];
        h2[tid] = fmaxf(a2, 0.f);
    }
    __syncthreads();
    if (tid < 3) {
        float a3 = b3[tid];
        #pragma unroll
        for (int k = 0; k < 64; ++k) a3 += W3[tid * 64 + k] * h2[k];
        lg[tid] = a3;
    }
    __syncthreads();
    if (tid == 0) {
        float m = fmaxf(lg[0], fmaxf(lg[1], lg[2]));
        float e0 = expf(lg[0] - m), e1 = expf(lg[1] - m), e2 = expf(lg[2] - m);
        float inv = 1.f / (e0 + e1 + e2);
        float p0 = e0 * inv, p1 = e1 * inv, p2 = e2 * inv;
        out[16 + ib * 3 + 0] = p0;
        out[16 + ib * 3 + 1] = p1;
        out[16 + ib * 3 + 2] = p2;
        int cid = 0; float bm = p0;
        if (p1 > bm) { bm = p1; cid = 1; }
        if (p2 > bm) { bm = p2; cid = 2; }
        out[ib] = (float)cid;
    }
}

// ====================== fallback path (round-2 pipeline) ====================
__global__ __launch_bounds__(256) void k_init(unsigned* mm, unsigned long long* hist64) {
    int t = blockIdx.x * 256 + threadIdx.x;
    hist64[t] = 0ull;
    if (t < IMG_B) { mm[2 * t] = 0xFFFFFFFFu; mm[2 * t + 1] = 0u; }
}

__global__ __launch_bounds__(320) void k_pass1(const float* __restrict__ img,
                                               double* __restrict__ partials,
                                               unsigned* __restrict__ mm) {
    int blk = blockIdx.x;
    int b   = blk >> 6;
    int r0  = (blk & 63) * 16;
    const float* base = img + (size_t)b * NPIX;
    int c = threadIdx.x;

    float fmn = FLT_MAX, fmx = -FLT_MAX;
    double s = 0.0, s2 = 0.0, ls = 0.0, ls2 = 0.0;

    for (int i = 0; i < 16; ++i) {
        int r = r0 + i;
        const float* rowf = base + (size_t)r * IMG_W;
        float4 m = ((const float4*)rowf)[c];
        float4 up = make_float4(0.f, 0.f, 0.f, 0.f);
        float4 dn = make_float4(0.f, 0.f, 0.f, 0.f);
        if (r > 0)          up = ((const float4*)(rowf - IMG_W))[c];
        if (r < IMG_H - 1)  dn = ((const float4*)(rowf + IMG_W))[c];
        float lft = (c > 0)   ? rowf[4 * c - 1] : 0.f;
        float rgt = (c < 319) ? rowf[4 * c + 4] : 0.f;

        fmn = fminf(fmn, fminf(fminf(m.x, m.y), fminf(m.z, m.w)));
        fmx = fmaxf(fmx, fmaxf(fmaxf(m.x, m.y), fmaxf(m.z, m.w)));
        s  += (double)m.x + (double)m.y + (double)m.z + (double)m.w;
        s2 += (double)m.x * m.x + (double)m.y * m.y + (double)m.z * m.z + (double)m.w * m.w;

        float l0 = up.x + dn.x + lft + m.y - 4.f * m.x;
        float l1 = up.y + dn.y + m.x + m.z - 4.f * m.y;
        float l2 = up.z + dn.z + m.y + m.w - 4.f * m.z;
        float l3 = up.w + dn.w + m.z + rgt - 4.f * m.w;
        ls  += (double)l0 + (double)l1 + (double)l2 + (double)l3;
        ls2 += (double)l0 * l0 + (double)l1 * l1 + (double)l2 * l2 + (double)l3 * l3;
    }
    for (int o = 32; o; o >>= 1) {
        s   += __shfl_down(s,   (unsigned)o, 64);
        s2  += __shfl_down(s2,  (unsigned)o, 64);
        ls  += __shfl_down(ls,  (unsigned)o, 64);
        ls2 += __shfl_down(ls2, (unsigned)o, 64);
        fmn = fminf(fmn, __shfl_down(fmn, (unsigned)o, 64));
        fmx = fmaxf(fmx, __shfl_down(fmx, (unsigned)o, 64));
    }
    __shared__ double rd[4][5];
    __shared__ float  rf[2][5];
    int lane = threadIdx.x & 63, wv = threadIdx.x >> 6;
    if (lane == 0) {
        rd[0][wv] = s; rd[1][wv] = s2; rd[2][wv] = ls; rd[3][wv] = ls2;
        rf[0][wv] = fmn; rf[1][wv] = fmx;
    }
    __syncthreads();
    if (threadIdx.x == 0) {
        double S = 0, S2 = 0, LS = 0, LS2 = 0;
        float mn = FLT_MAX, mx = -FLT_MAX;
        for (int i = 0; i < 5; ++i) {
            S += rd[0][i]; S2 += rd[1][i]; LS += rd[2][i]; LS2 += rd[3][i];
            mn = fminf(mn, rf[0][i]); mx = fmaxf(mx, rf[1][i]);
        }
        double* p = partials + (size_t)blk * 4;
        p[0] = S; p[1] = S2; p[2] = LS; p[3] = LS2;
        atomicMin(&mm[b * 2 + 0], encf(mn));
        atomicMax(&mm[b * 2 + 1], encf(mx));
    }
}

__global__ __launch_bounds__(256) void k_pass2(const float* __restrict__ img,
                                               const unsigned* __restrict__ mm,
                                               unsigned long long* __restrict__ hist64) {
    __shared__ unsigned lh[BINS];
    int b     = blockIdx.x / 64;
    int blkin = blockIdx.x % 64;
    lh[threadIdx.x] = 0u;
    __syncthreads();
    float fmn = decf(mm[b * 2 + 0]);
    float fmx = decf(mm[b * 2 + 1]);
    float rng = fmx - fmn;
    if (rng == 0.f) rng = 1.f;
    float inv = 1.f / rng;
    const float4* p = (const float4*)(img + (size_t)b * NPIX);
    for (int i = blkin * 256 + threadIdx.x; i < NPIX / 4; i += 64 * 256) {
        float4 v = p[i];
        #pragma unroll
        for (int j = 0; j < 4; ++j) {
            float vv = (j == 0) ? v.x : (j == 1) ? v.y : (j == 2) ? v.z : v.w;
            float x  = fminf(fmaxf((vv - fmn) * inv, 0.f), 1.f);
            float pp = x * 256.f - 0.5f;
            float fi = floorf(pp);
            int   i0 = (int)fi;
            float w1 = pp - fi;
            unsigned w1q = (unsigned)(w1 * FIXP + 0.5f);
            unsigned w0q = 65536u - w1q;
            if (i0 >= 0)       atomicAdd(&lh[i0], w0q);
            if (i0 < BINS - 1) atomicAdd(&lh[i0 + 1], w1q);
        }
    }
    __syncthreads();
    unsigned hv = lh[threadIdx.x];
    if (hv != 0u)
        atomicAdd(&hist64[b * BINS + threadIdx.x], (unsigned long long)hv);
}

__global__ __launch_bounds__(256) void k_pass3(const unsigned long long* __restrict__ hist64,
                                               const double* __restrict__ partials,
                                               const unsigned* __restrict__ mm,
                                               float* __restrict__ featsw,
                                               float* __restrict__ out) {
    int b = blockIdx.x, t = threadIdx.x;
    double h = (double)hist64[b * BINS + t] * (1.0 / 65536.0);
    __shared__ double red[4];
    __shared__ float red2[4];
    __shared__ double momx[4];
    double tot = h;
    for (int o = 32; o; o >>= 1) tot += __shfl_down(tot, (unsigned)o, 64);
    if ((t & 63) == 0) red[t >> 6] = tot;
    if (t < 64) {
        const double* p = partials + ((size_t)b * 64 + t) * 4;
        double q0 = p[0], q1 = p[1], q2 = p[2], q3 = p[3];
        for (int o = 32; o; o >>= 1) {
            q0 += __shfl_down(q0, (unsigned)o, 64);
            q1 += __shfl_down(q1, (unsigned)o, 64);
            q2 += __shfl_down(q2, (unsigned)o, 64);
            q3 += __shfl_down(q3, (unsigned)o, 64);
        }
        if (t == 0) { momx[0] = q0; momx[1] = q1; momx[2] = q2; momx[3] = q3; }
    }
    __syncthreads();
    double tot_all = red[0] + red[1] + red[2] + red[3];
    float hn = (float)(h / (tot_all + 1e-10));
    float ce = hn * log2f(hn + 1e-10f);
    for (int o = 32; o; o >>= 1) ce += __shfl_down(ce, (unsigned)o, 64);
    if ((t & 63) == 0) red2[t >> 6] = ce;
    __syncthreads();
    if (t == 0) {
        float ent = -(red2[0] + red2[1] + red2[2] + red2[3]) / 8.f;
        float gmax = -FLT_MAX;
        for (int i = 0; i < IMG_B; ++i) gmax = fmaxf(gmax, decf(mm[i * 2 + 1]));
        float sc = (gmax > 1.f) ? (1.f / 16383.f) : 1.f;
        double N = (double)NPIX;
        double S = momx[0], S2 = momx[1], LS = momx[2], LS2 = momx[3];
        double sc2 = (double)sc * (double)sc;
        float var  = (float)((S2  - S  * S  / N) / (N - 1.0) * sc2);
        float lvar = (float)((LS2 - LS * LS / N) / (N - 1.0) * sc2);
        float mn = decf(mm[b * 2 + 0]) * sc;
        float mx = decf(mm[b * 2 + 1]) * sc;
        float* fo = out + 64 + b * 5;
        fo[0] = var; fo[1] = mn; fo[2] = mx; fo[3] = ent; fo[4] = lvar;
        float* fw = featsw + b * 5;
        fw[0] = var; fw[1] = mn; fw[2] = mx; fw[3] = ent; fw[4] = lvar;
    }
}

__global__ __launch_bounds__(64) void k_pass4(const float* __restrict__ feats,
                                              const float* __restrict__ W1, const float* __restrict__ b1,
                                              const float* __restrict__ W2, const float* __restrict__ b2,
                                              const float* __restrict__ W3, const float* __restrict__ b3,
                                              float* __restrict__ out) {
    int t = threadIdx.x;
    int b = blockIdx.x;
    __shared__ float f[5], h1[64], h2[64], lg[3];
    if (t < 5) f[t] = feats[b * 5 + t];
    __syncthreads();
    float a = b1[t];
    #pragma unroll
    for (int k = 0; k < 5; ++k) a += W1[t * 5 + k] * f[k];
    h1[t] = fmaxf(a, 0.f);
    __syncthreads();
    float a2 = b2[t];
    #pragma unroll
    for (int k = 0; k < 64; ++k) a2 += W2[t * 64 + k] * h1[k];
    h2[t] = fmaxf(a2, 0.f);
    __syncthreads();
    if (t < 3) {
        float a3 = b3[t];
        #pragma unroll
        for (int k = 0; k < 64; ++k) a3 += W3[t * 64 + k] * h2[k];
        lg[t] = a3;
    }
    __syncthreads();
    if (t == 0) {
        float m = fmaxf(lg[0], fmaxf(lg[1], lg[2]));
        float e0 = expf(lg[0] - m), e1 = expf(lg[1] - m), e2 = expf(lg[2] - m);
        float inv = 1.f / (e0 + e1 + e2);
        float p0 = e0 * inv, p1 = e1 * inv, p2 = e2 * inv;
        out[16 + b * 3 + 0] = p0;
        out[16 + b * 3 + 1] = p1;
        out[16 + b * 3 + 2] = p2;
        int cid = 0; float bm = p0;
        if (p1 > bm) { bm = p1; cid = 1; }
        if (p2 > bm) { bm = p2; cid = 2; }
        out[b] = (float)cid;
    }
}

extern "C" void kernel_launch(void* const* d_in, const int* in_sizes, int n_in,
                              void* d_out, int out_size, void* d_ws, size_t ws_size,
                              hipStream_t stream) {
    const float* img = (const float*)d_in[0];
    const float* W1  = (const float*)d_in[1];
    const float* b1  = (const float*)d_in[2];
    const float* W2  = (const float*)d_in[3];
    const float* b2  = (const float*)d_in[4];
    const float* W3  = (const float*)d_in[5];
    const float* b3  = (const float*)d_in[6];
    float* out = (float*)d_out;

    char* ws = (char*)d_ws;
    double*   mom   = (double*)ws;                 // 1024*4 doubles
    uint2*    mmp   = (uint2*)(ws + 32768);        // 1024 uint2
    unsigned* bhist = (unsigned*)(ws + 40960);     // 1024*256 uints (1 MB)

    void* kargs[] = {(void*)&img, (void*)&W1, (void*)&b1, (void*)&W2, (void*)&b2,
                     (void*)&W3, (void*)&b3, (void*)&out, (void*)&mom, (void*)&mmp,
                     (void*)&bhist};
    hipError_t err = hipLaunchCooperativeKernel((const void*)k_fused,
                                                dim3(NBLK), dim3(NTHR),
                                                kargs, 0, stream);
    if (err != hipSuccess) {
        // fallback: proven round-2 multi-kernel pipeline
        double*             partials = (double*)ws;
        unsigned*           mm       = (unsigned*)(ws + 32768);
        unsigned long long* hist64   = (unsigned long long*)(ws + 32896);
        float*              featsw   = (float*)(ws + 65664);
        k_init <<<16, 256, 0, stream>>>(mm, hist64);
        k_pass1<<<IMG_B * 64, 320, 0, stream>>>(img, partials, mm);
        k_pass2<<<IMG_B * 64, 256, 0, stream>>>(img, mm, hist64);
        k_pass3<<<IMG_B, 256, 0, stream>>>(hist64, partials, mm, featsw, out);
        k_pass4<<<IMG_B, 64, 0, stream>>>(featsw, W1, b1, W2, b2, W3, b3, out);
    }
}

// Round 4
// 159.453 us; speedup vs baseline: 3.7436x; 3.7436x over previous
//
#include <hip/hip_runtime.h>
#include <cfloat>
#include <math.h>

#define IMG_B 16
#define IMG_H 1024
#define IMG_W 1280
#define NPIX (IMG_H * IMG_W)          // 1,310,720
#define BINS 256
#define SLICES 64                     // slices per image (16 rows each)
#define NBLK (IMG_B * SLICES)         // 1024
#define F4_PER_SLICE (16 * IMG_W / 4) // 5120
#define FIXP 65536.0f

// ---------- helpers ----------
__device__ __forceinline__ unsigned encf(float f) {
    unsigned u = __float_as_uint(f);
    return (u >> 31) ? ~u : (u | 0x80000000u);
}
__device__ __forceinline__ float decf(unsigned u) {
    unsigned b = (u & 0x80000000u) ? (u & 0x7fffffffu) : ~u;
    return __uint_as_float(b);
}

// ws layout (bytes):
//   mmp   : uint2[1024]      @ 0       per-slice (min,max) encoded       8 KB
//   mom   : double[1024*4]   @ 8192    per-slice S,S2,LS,LS2            32 KB
//   bhist : uint[1024*256]   @ 40960   per-slice fixed-point histogram   1 MB
// All fully overwritten every call -> no init kernel needed.

// ===================== Kernel 1: per-slice min/max (pure BW sweep) =========
__global__ __launch_bounds__(256) void k_minmax(const float* __restrict__ img,
                                                uint2* __restrict__ mmp) {
    const int blk = blockIdx.x;
    const int tid = threadIdx.x;
    const float4* p = (const float4*)img + (size_t)blk * F4_PER_SLICE;

    float fmn = FLT_MAX, fmx = -FLT_MAX;
    #pragma unroll 4
    for (int i = tid; i < F4_PER_SLICE; i += 256) {
        float4 v = p[i];
        fmn = fminf(fmn, fminf(fminf(v.x, v.y), fminf(v.z, v.w)));
        fmx = fmaxf(fmx, fmaxf(fmaxf(v.x, v.y), fmaxf(v.z, v.w)));
    }
    for (int o = 32; o; o >>= 1) {
        fmn = fminf(fmn, __shfl_down(fmn, (unsigned)o, 64));
        fmx = fmaxf(fmx, __shfl_down(fmx, (unsigned)o, 64));
    }
    __shared__ float rmn[4], rmx[4];
    int lane = tid & 63, wv = tid >> 6;
    if (lane == 0) { rmn[wv] = fmn; rmx[wv] = fmx; }
    __syncthreads();
    if (tid == 0) {
        float mn = fminf(fminf(rmn[0], rmn[1]), fminf(rmn[2], rmn[3]));
        float mx = fmaxf(fmaxf(rmx[0], rmx[1]), fmaxf(rmx[2], rmx[3]));
        mmp[blk] = make_uint2(encf(mn), encf(mx));
    }
}

// ===================== Kernel 2: moments + Laplacian + histogram ===========
__global__ __launch_bounds__(256) void k_main(const float* __restrict__ img,
                                              const uint2* __restrict__ mmp,
                                              double* __restrict__ mom,
                                              unsigned* __restrict__ bhist) {
    const int blk = blockIdx.x;
    const int tid = threadIdx.x;
    const int b   = blk >> 6;           // image
    const int sl  = blk & 63;           // slice (16 rows)
    const int lane = tid & 63, wv = tid >> 6;

    __shared__ unsigned lh[BINS];
    __shared__ float sh_mm[2];
    __shared__ float swred[4][4];

    // image min/max from the 64 slice partials
    if (tid < 64) {
        uint2 e = mmp[b * 64 + tid];
        unsigned emn = e.x, emx = e.y;
        for (int o = 32; o; o >>= 1) {
            emn = min(emn, (unsigned)__shfl_down(emn, (unsigned)o, 64));
            emx = max(emx, (unsigned)__shfl_down(emx, (unsigned)o, 64));
        }
        if (tid == 0) { sh_mm[0] = decf(emn); sh_mm[1] = decf(emx); }
    }
    lh[tid] = 0u;
    __syncthreads();

    const float fmn = sh_mm[0], fmx = sh_mm[1];
    float rng = fmx - fmn;
    if (rng == 0.f) rng = 1.f;
    const float inv = 1.f / rng;

    const float* base = img + (size_t)b * NPIX;
    const int r0 = sl * 16;

    float fs = 0.f, fs2 = 0.f, fls = 0.f, fls2 = 0.f;

    #pragma unroll 2
    for (int k = 0; k < 20; ++k) {               // 20*256 = 5120 float4
        int i   = tid + k * 256;
        int ri  = i / 320;                        // row within slice
        int c   = i - ri * 320;                   // float4 col 0..319
        int r   = r0 + ri;
        const float* rowf = base + (size_t)r * IMG_W;
        float4 m = ((const float4*)rowf)[c];
        float4 up = make_float4(0.f, 0.f, 0.f, 0.f);
        float4 dn = make_float4(0.f, 0.f, 0.f, 0.f);
        if (r > 0)          up = ((const float4*)(rowf - IMG_W))[c];
        if (r < IMG_H - 1)  dn = ((const float4*)(rowf + IMG_W))[c];
        float lft = (c > 0)   ? rowf[4 * c - 1] : 0.f;
        float rgt = (c < 319) ? rowf[4 * c + 4] : 0.f;

        // moments (tree-summed locals -> 1 dependent add per chain per iter)
        fs  += (m.x + m.y) + (m.z + m.w);
        fs2 += (m.x * m.x + m.y * m.y) + (m.z * m.z + m.w * m.w);

        float l0 = up.x + dn.x + lft + m.y - 4.f * m.x;
        float l1 = up.y + dn.y + m.x + m.z - 4.f * m.y;
        float l2 = up.z + dn.z + m.y + m.w - 4.f * m.z;
        float l3 = up.w + dn.w + m.z + rgt - 4.f * m.w;
        fls  += (l0 + l1) + (l2 + l3);
        fls2 += (l0 * l0 + l1 * l1) + (l2 * l2 + l3 * l3);

        // fixed-point soft histogram
        #pragma unroll
        for (int j = 0; j < 4; ++j) {
            float vv = (j == 0) ? m.x : (j == 1) ? m.y : (j == 2) ? m.z : m.w;
            float x  = fminf(fmaxf((vv - fmn) * inv, 0.f), 1.f);
            float pp = x * 256.f - 0.5f;
            float fi = floorf(pp);
            int   i0 = (int)fi;
            float w1 = pp - fi;
            unsigned w1q = (unsigned)(w1 * FIXP + 0.5f);
            unsigned w0q = 65536u - w1q;
            if (i0 >= 0)        atomicAdd(&lh[i0], w0q);
            if (i0 < BINS - 1)  atomicAdd(&lh[i0 + 1], w1q);
        }
    }

    // block-reduce moments (f32 -> f64 at the end)
    for (int o = 32; o; o >>= 1) {
        fs   += __shfl_down(fs,   (unsigned)o, 64);
        fs2  += __shfl_down(fs2,  (unsigned)o, 64);
        fls  += __shfl_down(fls,  (unsigned)o, 64);
        fls2 += __shfl_down(fls2, (unsigned)o, 64);
    }
    if (lane == 0) {
        swred[0][wv] = fs;  swred[1][wv] = fs2;
        swred[2][wv] = fls; swred[3][wv] = fls2;
    }
    __syncthreads();
    if (tid == 0) {
        double S  = (double)swred[0][0] + (double)swred[0][1] + (double)swred[0][2] + (double)swred[0][3];
        double S2 = (double)swred[1][0] + (double)swred[1][1] + (double)swred[1][2] + (double)swred[1][3];
        double LS  = (double)swred[2][0] + (double)swred[2][1] + (double)swred[2][2] + (double)swred[2][3];
        double LS2 = (double)swred[3][0] + (double)swred[3][1] + (double)swred[3][2] + (double)swred[3][3];
        mom[blk * 4 + 0] = S;  mom[blk * 4 + 1] = S2;
        mom[blk * 4 + 2] = LS; mom[blk * 4 + 3] = LS2;
    }
    bhist[blk * BINS + tid] = lh[tid];           // contention-free
}

// ===================== Kernel 3: reduce + feats + MLP ======================
__global__ __launch_bounds__(256) void k_final(
    const unsigned* __restrict__ bhist, const double* __restrict__ mom,
    const uint2* __restrict__ mmp,
    const float* __restrict__ W1, const float* __restrict__ b1,
    const float* __restrict__ W2, const float* __restrict__ b2,
    const float* __restrict__ W3, const float* __restrict__ b3,
    float* __restrict__ out)
{
    const int ib = blockIdx.x;    // image
    const int tid = threadIdx.x;
    const int lane = tid & 63, wv = tid >> 6;

    __shared__ double dred[4];
    __shared__ float  fred[4];
    __shared__ double smom[4];
    __shared__ unsigned smm2[2];
    __shared__ unsigned sgm[4];
    __shared__ float f5[5], h1[64], h2[64], lg[3];

    // per-bin total over 64 slice histograms (exact in double)
    double h = 0.0;
    for (int s = 0; s < 64; ++s)
        h += (double)bhist[(ib * 64 + s) * BINS + tid];

    double tot = h;
    for (int o = 32; o; o >>= 1) tot += __shfl_down(tot, (unsigned)o, 64);
    if (lane == 0) dred[wv] = tot;
    __syncthreads();
    tot = dred[0] + dred[1] + dred[2] + dred[3];

    double hv = h * (1.0 / 65536.0);
    double tv = tot * (1.0 / 65536.0);
    float hn = (float)(hv / (tv + 1e-10));
    float ce = hn * log2f(hn + 1e-10f);
    for (int o = 32; o; o >>= 1) ce += __shfl_down(ce, (unsigned)o, 64);
    if (lane == 0) fred[wv] = ce;

    if (tid < 64) {   // moments + image min/max
        double q0 = mom[(ib * 64 + tid) * 4 + 0];
        double q1 = mom[(ib * 64 + tid) * 4 + 1];
        double q2 = mom[(ib * 64 + tid) * 4 + 2];
        double q3 = mom[(ib * 64 + tid) * 4 + 3];
        uint2 e = mmp[ib * 64 + tid];
        unsigned emn = e.x, emx = e.y;
        for (int o = 32; o; o >>= 1) {
            q0 += __shfl_down(q0, (unsigned)o, 64);
            q1 += __shfl_down(q1, (unsigned)o, 64);
            q2 += __shfl_down(q2, (unsigned)o, 64);
            q3 += __shfl_down(q3, (unsigned)o, 64);
            emn = min(emn, (unsigned)__shfl_down(emn, (unsigned)o, 64));
            emx = max(emx, (unsigned)__shfl_down(emx, (unsigned)o, 64));
        }
        if (tid == 0) {
            smom[0] = q0; smom[1] = q1; smom[2] = q2; smom[3] = q3;
            smm2[0] = emn; smm2[1] = emx;
        }
    }
    {   // global max over all 1024 slice maxima (scale decision)
        unsigned g = max(max(mmp[tid].y, mmp[256 + tid].y),
                         max(mmp[512 + tid].y, mmp[768 + tid].y));
        for (int o = 32; o; o >>= 1)
            g = max(g, (unsigned)__shfl_down(g, (unsigned)o, 64));
        if (lane == 0) sgm[wv] = g;
    }
    __syncthreads();

    if (tid == 0) {
        float ent = -(fred[0] + fred[1] + fred[2] + fred[3]) / 8.f;  // /log2(256)
        float gmax = decf(max(max(sgm[0], sgm[1]), max(sgm[2], sgm[3])));
        float sc = (gmax > 1.f) ? (1.f / 16383.f) : 1.f;
        double N = (double)NPIX;
        double S = smom[0], S2 = smom[1], LS = smom[2], LS2 = smom[3];
        double sc2 = (double)sc * (double)sc;
        float var  = (float)((S2  - S  * S  / N) / (N - 1.0) * sc2);
        float lvar = (float)((LS2 - LS * LS / N) / (N - 1.0) * sc2);
        float mn = decf(smm2[0]) * sc;
        float mx = decf(smm2[1]) * sc;
        float* fo = out + 64 + ib * 5;
        fo[0] = var; fo[1] = mn; fo[2] = mx; fo[3] = ent; fo[4] = lvar;
        f5[0] = var; f5[1] = mn; f5[2] = mx; f5[3] = ent; f5[4] = lvar;
    }
    __syncthreads();

    // tiny MLP
    if (tid < 64) {
        float a = b1[tid];
        #pragma unroll
        for (int k = 0; k < 5; ++k) a += W1[tid * 5 + k] * f5[k];
        h1[tid] = fmaxf(a, 0.f);
    }
    __syncthreads();
    if (tid < 64) {
        float a2 = b2[tid];
        #pragma unroll
        for (int k = 0; k < 64; ++k) a2 += W2[tid * 64 + k] * h1[k];
        h2[tid] = fmaxf(a2, 0.f);
    }
    __syncthreads();
    if (tid < 3) {
        float a3 = b3[tid];
        #pragma unroll
        for (int k = 0; k < 64; ++k) a3 += W3[tid * 64 + k] * h2[k];
        lg[tid] = a3;
    }
    __syncthreads();
    if (tid == 0) {
        float m = fmaxf(lg[0], fmaxf(lg[1], lg[2]));
        float e0 = expf(lg[0] - m), e1 = expf(lg[1] - m), e2 = expf(lg[2] - m);
        float inv = 1.f / (e0 + e1 + e2);
        float p0 = e0 * inv, p1 = e1 * inv, p2 = e2 * inv;
        out[16 + ib * 3 + 0] = p0;
        out[16 + ib * 3 + 1] = p1;
        out[16 + ib * 3 + 2] = p2;
        int cid = 0; float bm = p0;
        if (p1 > bm) { bm = p1; cid = 1; }
        if (p2 > bm) { bm = p2; cid = 2; }
        out[ib] = (float)cid;
    }
}

extern "C" void kernel_launch(void* const* d_in, const int* in_sizes, int n_in,
                              void* d_out, int out_size, void* d_ws, size_t ws_size,
                              hipStream_t stream) {
    const float* img = (const float*)d_in[0];
    const float* W1  = (const float*)d_in[1];
    const float* b1  = (const float*)d_in[2];
    const float* W2  = (const float*)d_in[3];
    const float* b2  = (const float*)d_in[4];
    const float* W3  = (const float*)d_in[5];
    const float* b3  = (const float*)d_in[6];
    float* out = (float*)d_out;

    char* ws = (char*)d_ws;
    uint2*    mmp   = (uint2*)ws;                 // 1024 uint2     (8 KB)
    double*   mom   = (double*)(ws + 8192);       // 1024*4 double  (32 KB)
    unsigned* bhist = (unsigned*)(ws + 40960);    // 1024*256 uint  (1 MB)

    k_minmax<<<NBLK, 256, 0, stream>>>(img, mmp);
    k_main  <<<NBLK, 256, 0, stream>>>(img, mmp, mom, bhist);
    k_final <<<IMG_B, 256, 0, stream>>>(bhist, mom, mmp,
                                        W1, b1, W2, b2, W3, b3, out);
}

// Round 5
// 158.067 us; speedup vs baseline: 3.7764x; 1.0088x over previous
//
#include <hip/hip_runtime.h>
#include <cfloat>
#include <math.h>

#define IMG_B 16
#define IMG_H 1024
#define IMG_W 1280
#define NPIX (IMG_H * IMG_W)          // 1,310,720
#define BINS 256
#define SLICES 64                     // slices per image (16 rows each)
#define NBLK (IMG_B * SLICES)         // 1024
#define F4_PER_SLICE (16 * IMG_W / 4) // 5120

// ---------- helpers ----------
__device__ __forceinline__ unsigned encf(float f) {
    unsigned u = __float_as_uint(f);
    return (u >> 31) ? ~u : (u | 0x80000000u);
}
__device__ __forceinline__ float decf(unsigned u) {
    unsigned b = (u & 0x80000000u) ? (u & 0x7fffffffu) : ~u;
    return __uint_as_float(b);
}

// ws layout (bytes):
//   mmp   : uint2[1024]      @ 0       per-slice (min,max) encoded       8 KB
//   mom   : double[1024*4]   @ 8192    per-slice S,S2,LS,LS2            32 KB
//   bhist : uint[1024*256]   @ 40960   per-slice fixed-point histogram   1 MB
// All fully overwritten every call -> no init kernel needed.

// ========== Kernel 1: min/max + moments + Laplacian (HBM-bound pass) =======
__global__ __launch_bounds__(256) void k_pre(const float* __restrict__ img,
                                             uint2* __restrict__ mmp,
                                             double* __restrict__ mom) {
    const int blk = blockIdx.x;
    const int tid = threadIdx.x;
    const int b   = blk >> 6;           // image
    const int sl  = blk & 63;           // slice (16 rows)
    const int lane = tid & 63, wv = tid >> 6;

    const float* base = img + (size_t)b * NPIX;
    const int r0 = sl * 16;

    float fs = 0.f, fs2 = 0.f, fls = 0.f, fls2 = 0.f;
    float fmn = FLT_MAX, fmx = -FLT_MAX;

    #pragma unroll 2
    for (int k = 0; k < 20; ++k) {               // 20*256 = 5120 float4
        int i   = tid + k * 256;
        int ri  = i / 320;                        // row within slice
        int c   = i - ri * 320;                   // float4 col 0..319
        int r   = r0 + ri;
        const float* rowf = base + (size_t)r * IMG_W;
        float4 m = ((const float4*)rowf)[c];
        float4 up = make_float4(0.f, 0.f, 0.f, 0.f);
        float4 dn = make_float4(0.f, 0.f, 0.f, 0.f);
        if (r > 0)          up = ((const float4*)(rowf - IMG_W))[c];
        if (r < IMG_H - 1)  dn = ((const float4*)(rowf + IMG_W))[c];
        float lft = (c > 0)   ? rowf[4 * c - 1] : 0.f;
        float rgt = (c < 319) ? rowf[4 * c + 4] : 0.f;

        fs  += (m.x + m.y) + (m.z + m.w);
        fs2 += (m.x * m.x + m.y * m.y) + (m.z * m.z + m.w * m.w);
        fmn = fminf(fmn, fminf(fminf(m.x, m.y), fminf(m.z, m.w)));
        fmx = fmaxf(fmx, fmaxf(fmaxf(m.x, m.y), fmaxf(m.z, m.w)));

        float l0 = up.x + dn.x + lft + m.y - 4.f * m.x;
        float l1 = up.y + dn.y + m.x + m.z - 4.f * m.y;
        float l2 = up.z + dn.z + m.y + m.w - 4.f * m.z;
        float l3 = up.w + dn.w + m.z + rgt - 4.f * m.w;
        fls  += (l0 + l1) + (l2 + l3);
        fls2 += (l0 * l0 + l1 * l1) + (l2 * l2 + l3 * l3);
    }

    for (int o = 32; o; o >>= 1) {
        fs   += __shfl_down(fs,   (unsigned)o, 64);
        fs2  += __shfl_down(fs2,  (unsigned)o, 64);
        fls  += __shfl_down(fls,  (unsigned)o, 64);
        fls2 += __shfl_down(fls2, (unsigned)o, 64);
        fmn = fminf(fmn, __shfl_down(fmn, (unsigned)o, 64));
        fmx = fmaxf(fmx, __shfl_down(fmx, (unsigned)o, 64));
    }
    __shared__ float swred[4][4];
    __shared__ float rmn[4], rmx[4];
    if (lane == 0) {
        swred[0][wv] = fs;  swred[1][wv] = fs2;
        swred[2][wv] = fls; swred[3][wv] = fls2;
        rmn[wv] = fmn; rmx[wv] = fmx;
    }
    __syncthreads();
    if (tid == 0) {
        double S   = (double)swred[0][0] + (double)swred[0][1] + (double)swred[0][2] + (double)swred[0][3];
        double S2  = (double)swred[1][0] + (double)swred[1][1] + (double)swred[1][2] + (double)swred[1][3];
        double LS  = (double)swred[2][0] + (double)swred[2][1] + (double)swred[2][2] + (double)swred[2][3];
        double LS2 = (double)swred[3][0] + (double)swred[3][1] + (double)swred[3][2] + (double)swred[3][3];
        mom[blk * 4 + 0] = S;  mom[blk * 4 + 1] = S2;
        mom[blk * 4 + 2] = LS; mom[blk * 4 + 3] = LS2;
        float mn = fminf(fminf(rmn[0], rmn[1]), fminf(rmn[2], rmn[3]));
        float mx = fmaxf(fmaxf(rmx[0], rmx[1]), fmaxf(rmx[2], rmx[3]));
        mmp[blk] = make_uint2(encf(mn), encf(mx));
    }
}

// ========== Kernel 2: packed-u64 soft histogram (1 DS atomic / pixel) ======
// Decomposition: per pixel let i0=floor(clamp(p,-0.5,255.5)), w1q=round((p-i0)*2^16).
// Accumulate A[i0+1] += (1<<32) | w1q.  Then
//   h_fix[k] = 65536*hi(A[k+1]) - lo(A[k+1]) + lo(A[k]),  k in [0,256).
// This equals the two-sided triangular scatter with w0q = 65536 - w1q.
__global__ __launch_bounds__(256) void k_hist(const float* __restrict__ img,
                                              const uint2* __restrict__ mmp,
                                              unsigned* __restrict__ bhist) {
    const int blk = blockIdx.x;
    const int tid = threadIdx.x;
    const int b   = blk >> 6;

    __shared__ unsigned long long lh64[BINS + 1];
    __shared__ float sh_ab[2];

    // image min/max from the 64 slice partials
    if (tid < 64) {
        uint2 e = mmp[b * 64 + tid];
        unsigned emn = e.x, emx = e.y;
        for (int o = 32; o; o >>= 1) {
            emn = min(emn, (unsigned)__shfl_down(emn, (unsigned)o, 64));
            emx = max(emx, (unsigned)__shfl_down(emx, (unsigned)o, 64));
        }
        if (tid == 0) {
            float fmn = decf(emn), fmx = decf(emx);
            float rng = fmx - fmn;
            if (rng == 0.f) rng = 1.f;
            float a = 256.f / rng;                 // pp = v*a + bb
            float bb = -fmn * a - 0.5f;
            sh_ab[0] = a; sh_ab[1] = bb;
        }
    }
    lh64[tid] = 0ull;
    if (tid == 0) lh64[BINS] = 0ull;
    __syncthreads();

    const float a = sh_ab[0], bb = sh_ab[1];

    const float4* p = (const float4*)img + (size_t)blk * F4_PER_SLICE;
    #pragma unroll 2
    for (int k = 0; k < 20; ++k) {               // 20*256 = 5120 float4
        float4 v = p[tid + k * 256];
        #pragma unroll
        for (int j = 0; j < 4; ++j) {
            float vv = (j == 0) ? v.x : (j == 1) ? v.y : (j == 2) ? v.z : v.w;
            float pp = fminf(fmaxf(vv * a + bb, -0.5f), 255.5f);
            float fi = floorf(pp);
            int   i0 = (int)fi;                   // -1 .. 255
            unsigned w1q = (unsigned)((pp - fi) * 65536.f + 0.5f);
            atomicAdd(&lh64[i0 + 1], 0x100000000ull + (unsigned long long)w1q);
        }
    }
    __syncthreads();

    unsigned long long a0 = lh64[tid];
    unsigned long long a1 = lh64[tid + 1];
    unsigned long long h  = ((a1 >> 32) << 16) - (a1 & 0xffffffffull) + (a0 & 0xffffffffull);
    bhist[blk * BINS + tid] = (unsigned)h;       // < 2^31, contention-free
}

// ===================== Kernel 3: reduce + feats + MLP ======================
__global__ __launch_bounds__(256) void k_final(
    const unsigned* __restrict__ bhist, const double* __restrict__ mom,
    const uint2* __restrict__ mmp,
    const float* __restrict__ W1, const float* __restrict__ b1,
    const float* __restrict__ W2, const float* __restrict__ b2,
    const float* __restrict__ W3, const float* __restrict__ b3,
    float* __restrict__ out)
{
    const int ib = blockIdx.x;    // image
    const int tid = threadIdx.x;
    const int lane = tid & 63, wv = tid >> 6;

    __shared__ double dred[4];
    __shared__ float  fred[4];
    __shared__ double smom[4];
    __shared__ unsigned smm2[2];
    __shared__ unsigned sgm[4];
    __shared__ float f5[5], h1[64], h2[64], lg[3];

    // per-bin total over 64 slice histograms (exact in double)
    double h = 0.0;
    for (int s = 0; s < 64; ++s)
        h += (double)bhist[(ib * 64 + s) * BINS + tid];

    double tot = h;
    for (int o = 32; o; o >>= 1) tot += __shfl_down(tot, (unsigned)o, 64);
    if (lane == 0) dred[wv] = tot;
    __syncthreads();
    tot = dred[0] + dred[1] + dred[2] + dred[3];

    double hv = h * (1.0 / 65536.0);
    double tv = tot * (1.0 / 65536.0);
    float hn = (float)(hv / (tv + 1e-10));
    float ce = hn * log2f(hn + 1e-10f);
    for (int o = 32; o; o >>= 1) ce += __shfl_down(ce, (unsigned)o, 64);
    if (lane == 0) fred[wv] = ce;

    if (tid < 64) {   // moments + image min/max
        double q0 = mom[(ib * 64 + tid) * 4 + 0];
        double q1 = mom[(ib * 64 + tid) * 4 + 1];
        double q2 = mom[(ib * 64 + tid) * 4 + 2];
        double q3 = mom[(ib * 64 + tid) * 4 + 3];
        uint2 e = mmp[ib * 64 + tid];
        unsigned emn = e.x, emx = e.y;
        for (int o = 32; o; o >>= 1) {
            q0 += __shfl_down(q0, (unsigned)o, 64);
            q1 += __shfl_down(q1, (unsigned)o, 64);
            q2 += __shfl_down(q2, (unsigned)o, 64);
            q3 += __shfl_down(q3, (unsigned)o, 64);
            emn = min(emn, (unsigned)__shfl_down(emn, (unsigned)o, 64));
            emx = max(emx, (unsigned)__shfl_down(emx, (unsigned)o, 64));
        }
        if (tid == 0) {
            smom[0] = q0; smom[1] = q1; smom[2] = q2; smom[3] = q3;
            smm2[0] = emn; smm2[1] = emx;
        }
    }
    {   // global max over all 1024 slice maxima (scale decision)
        unsigned g = max(max(mmp[tid].y, mmp[256 + tid].y),
                         max(mmp[512 + tid].y, mmp[768 + tid].y));
        for (int o = 32; o; o >>= 1)
            g = max(g, (unsigned)__shfl_down(g, (unsigned)o, 64));
        if (lane == 0) sgm[wv] = g;
    }
    __syncthreads();

    if (tid == 0) {
        float ent = -(fred[0] + fred[1] + fred[2] + fred[3]) / 8.f;  // /log2(256)
        float gmax = decf(max(max(sgm[0], sgm[1]), max(sgm[2], sgm[3])));
        float sc = (gmax > 1.f) ? (1.f / 16383.f) : 1.f;
        double N = (double)NPIX;
        double S = smom[0], S2 = smom[1], LS = smom[2], LS2 = smom[3];
        double sc2 = (double)sc * (double)sc;
        float var  = (float)((S2  - S  * S  / N) / (N - 1.0) * sc2);
        float lvar = (float)((LS2 - LS * LS / N) / (N - 1.0) * sc2);
        float mn = decf(smm2[0]) * sc;
        float mx = decf(smm2[1]) * sc;
        float* fo = out + 64 + ib * 5;
        fo[0] = var; fo[1] = mn; fo[2] = mx; fo[3] = ent; fo[4] = lvar;
        f5[0] = var; f5[1] = mn; f5[2] = mx; f5[3] = ent; f5[4] = lvar;
    }
    __syncthreads();

    // tiny MLP
    if (tid < 64) {
        float aa = b1[tid];
        #pragma unroll
        for (int k = 0; k < 5; ++k) aa += W1[tid * 5 + k] * f5[k];
        h1[tid] = fmaxf(aa, 0.f);
    }
    __syncthreads();
    if (tid < 64) {
        float a2 = b2[tid];
        #pragma unroll
        for (int k = 0; k < 64; ++k) a2 += W2[tid * 64 + k] * h1[k];
        h2[tid] = fmaxf(a2, 0.f);
    }
    __syncthreads();
    if (tid < 3) {
        float a3 = b3[tid];
        #pragma unroll
        for (int k = 0; k < 64; ++k) a3 += W3[tid * 64 + k] * h2[k];
        lg[tid] = a3;
    }
    __syncthreads();
    if (tid == 0) {
        float m = fmaxf(lg[0], fmaxf(lg[1], lg[2]));
        float e0 = expf(lg[0] - m), e1 = expf(lg[1] - m), e2 = expf(lg[2] - m);
        float inv = 1.f / (e0 + e1 + e2);
        float p0 = e0 * inv, p1 = e1 * inv, p2 = e2 * inv;
        out[16 + ib * 3 + 0] = p0;
        out[16 + ib * 3 + 1] = p1;
        out[16 + ib * 3 + 2] = p2;
        int cid = 0; float bm = p0;
        if (p1 > bm) { bm = p1; cid = 1; }
        if (p2 > bm) { bm = p2; cid = 2; }
        out[ib] = (float)cid;
    }
}

extern "C" void kernel_launch(void* const* d_in, const int* in_sizes, int n_in,
                              void* d_out, int out_size, void* d_ws, size_t ws_size,
                              hipStream_t stream) {
    const float* img = (const float*)d_in[0];
    const float* W1  = (const float*)d_in[1];
    const float* b1  = (const float*)d_in[2];
    const float* W2  = (const float*)d_in[3];
    const float* b2  = (const float*)d_in[4];
    const float* W3  = (const float*)d_in[5];
    const float* b3  = (const float*)d_in[6];
    float* out = (float*)d_out;

    char* ws = (char*)d_ws;
    uint2*    mmp   = (uint2*)ws;                 // 1024 uint2     (8 KB)
    double*   mom   = (double*)(ws + 8192);       // 1024*4 double  (32 KB)
    unsigned* bhist = (unsigned*)(ws + 40960);    // 1024*256 uint  (1 MB)

    k_pre  <<<NBLK, 256, 0, stream>>>(img, mmp, mom);
    k_hist <<<NBLK, 256, 0, stream>>>(img, mmp, bhist);
    k_final<<<IMG_B, 256, 0, stream>>>(bhist, mom, mmp,
                                       W1, b1, W2, b2, W3, b3, out);
}